// Round 18
// baseline (999.457 us; speedup 1.0000x reference)
//
#include <hip/hip_runtime.h>
#include <hip/hip_bf16.h>

// RNNLayer: B=64, T=512, D_IN=D_H=D_OUT=1024.
// h_{t+1} = A h_t + u_t  (A = Wrh, u_t = x_t@Wxh^T + bh);  o_t = x_t@Wxo^T + h_t@Wro^T + bo
// Scan decomposition (sequential depth 511 -> 31 + 15):
//   tree:  v1=A u+u', v2=A2 v1+v1', v3=A4 v2+v2', v4=A8 v3+v3'  (4 fused GEMM dispatches)
//   chain: h_{16(k+1)} = A16 h_{16k} + v4_k       (31 flag-sync steps, 64 WGs)
//   fill:  h_{16k+tau+1} = A h_{16k+tau} + u      (15 flag-sync steps, 256 WGs, nch=8)
// r17 -> r18: defer the Out round-trip. If ws_size >= 208 MB: gemm1 writes the
// x-output-projection as f16 Xo (64 MB) instead of f32 Out (256 MB); gemm2 does
// a single pure write Out = Xo + Hs@Wro^T (no Out read). Saves ~384 MB HBM
// traffic. Runtime fallback (useXo=0) reproduces r17 exactly if ws is small.

typedef _Float16 f16;
typedef _Float16 f16x8 __attribute__((ext_vector_type(8)));
typedef _Float16 f16x4 __attribute__((ext_vector_type(4)));
typedef float f32x4 __attribute__((ext_vector_type(4)));
typedef int i32x4 __attribute__((ext_vector_type(4)));

#define T_LEN 512
#define BATCH 64
#define M_TOT (BATCH * T_LEN)   // 32768

// Hs slab layout (per t): [bg 4][cblk 128][b 16][8] f16 = 65536 elems (128 KB)
// Xh slab layout (per t): [bg 4][b 16][col 1024]  f16 (b-major)
// Xo layout: [b][t][1024] f16 (same index space as Out)

// ---------- prep: stacked fp16 weights + X f32->f16 (fused) ----------
__global__ void k_prep(const float* __restrict__ Wh, const float* __restrict__ Wo,
                       const float* __restrict__ X,
                       f16* __restrict__ Wx, f16* __restrict__ Wr, f16* __restrict__ Xf) {
    int bid = blockIdx.x;
    if (bid < 16384) {
        size_t i = ((size_t)bid * 256 + threadIdx.x) * 8;
        float4 a = *reinterpret_cast<const float4*>(X + i);
        float4 b = *reinterpret_cast<const float4*>(X + i + 4);
        f16x8 v;
        v[0]=(f16)a.x; v[1]=(f16)a.y; v[2]=(f16)a.z; v[3]=(f16)a.w;
        v[4]=(f16)b.x; v[5]=(f16)b.y; v[6]=(f16)b.z; v[7]=(f16)b.w;
        *reinterpret_cast<f16x8*>(Xf + i) = v;
    } else {
        int n = bid - 16384;             // 0..2047
        int t4 = threadIdx.x * 4;        // 0..1020
        const float* src = (n < 1024) ? (Wh + (size_t)n * 2048)
                                      : (Wo + (size_t)(n - 1024) * 2048);
        float4 a = *reinterpret_cast<const float4*>(src + t4);
        float4 b = *reinterpret_cast<const float4*>(src + 1024 + t4);
        f16x4 va, vb;
        va[0]=(f16)a.x; va[1]=(f16)a.y; va[2]=(f16)a.z; va[3]=(f16)a.w;
        vb[0]=(f16)b.x; vb[1]=(f16)b.y; vb[2]=(f16)b.z; vb[3]=(f16)b.w;
        *reinterpret_cast<f16x4*>(Wx + (size_t)n*1024 + t4) = va;
        *reinterpret_cast<f16x4*>(Wr + (size_t)n*1024 + t4) = vb;
    }
}

// ---------- init: Hs[0] from H0 (packed) + zero both flag banks (fused) ----------
__global__ void k_init(const float* __restrict__ H0, f16* __restrict__ Hs,
                       unsigned int* __restrict__ flags) {
    int bid = blockIdx.x;
    if (bid < 32) {
        int tid = bid * 256 + threadIdx.x;   // 8192
        int b = tid >> 7, kb = tid & 127;
        float4 x0 = *reinterpret_cast<const float4*>(H0 + (size_t)b*1024 + kb*8);
        float4 x1 = *reinterpret_cast<const float4*>(H0 + (size_t)b*1024 + kb*8 + 4);
        f16x8 v;
        v[0]=(f16)x0.x; v[1]=(f16)x0.y; v[2]=(f16)x0.z; v[3]=(f16)x0.w;
        v[4]=(f16)x1.x; v[5]=(f16)x1.y; v[6]=(f16)x1.z; v[7]=(f16)x1.w;
        size_t idx = (size_t)(b >> 4)*16384 + (size_t)kb*128 + (size_t)(b & 15)*8;
        *reinterpret_cast<f16x8*>(Hs + idx) = v;
    } else {
        flags[(bid - 32) * 256 + threadIdx.x] = 0;   // 16 blocks -> 4096 u32 (16 KB)
    }
}

// ---------- phase 1: input projection GEMM (m97 structure, BK=32) ----------
// grid (16 n-tiles, 256 m-tiles). Xh writes b-major; o-half -> Xo f16 (useXo)
// or Out f32 (fallback).
__global__ __launch_bounds__(256) void k_gemm1(
    const f16* __restrict__ Af, const f16* __restrict__ Bm,
    const float* __restrict__ bh, const float* __restrict__ bo,
    f16* __restrict__ Xh, float* __restrict__ Out, f16* __restrict__ Xo, int useXo)
{
    __shared__ f16 As[128*32];   // 8 KB, linear row-major [128][32]
    __shared__ f16 Bs[128*32];   // 8 KB
    int m0 = blockIdx.y * 128;
    int n0 = blockIdx.x * 128;
    int t = threadIdx.x;
    int l = t & 63, w = t >> 6;
    int wm = w >> 1, wn = w & 1;
    int lm = l & 15, lh = l >> 4;

    f32x4 acc[4][4];
    #pragma unroll
    for (int i = 0; i < 4; i++)
        #pragma unroll
        for (int j = 0; j < 4; j++) acc[i][j] = (f32x4){0.f,0.f,0.f,0.f};

    const size_t lgo = (size_t)(l >> 2) * 2048 + (size_t)(l & 3) * 16;

    for (int kt = 0; kt < 32; ++kt) {
        __syncthreads();
        {
            const char* ga = (const char*)(Af + (size_t)(m0 + w*32) * 1024 + kt*32);
            const char* gb = (const char*)(Bm + (size_t)(n0 + w*32) * 1024 + kt*32);
            char* la = (char*)As + w * 2048;
            char* lb = (char*)Bs + w * 2048;
            #pragma unroll
            for (int j = 0; j < 2; ++j) {
                __builtin_amdgcn_global_load_lds(
                    (const __attribute__((address_space(1))) void*)(ga + (size_t)j*32768 + lgo),
                    (__attribute__((address_space(3))) void*)(la + j*1024), 16, 0, 0);
                __builtin_amdgcn_global_load_lds(
                    (const __attribute__((address_space(1))) void*)(gb + (size_t)j*32768 + lgo),
                    (__attribute__((address_space(3))) void*)(lb + j*1024), 16, 0, 0);
            }
        }
        asm volatile("s_waitcnt vmcnt(0)" ::: "memory");
        __syncthreads();

        f16x8 af[4], bf[4];
        #pragma unroll
        for (int i = 0; i < 4; i++)
            af[i] = *reinterpret_cast<const f16x8*>(As + (64*wm + 16*i + lm)*32 + 8*lh);
        #pragma unroll
        for (int j = 0; j < 4; j++)
            bf[j] = *reinterpret_cast<const f16x8*>(Bs + (64*wn + 16*j + lm)*32 + 8*lh);
        #pragma unroll
        for (int i = 0; i < 4; i++)
            #pragma unroll
            for (int j = 0; j < 4; j++)
                acc[i][j] = __builtin_amdgcn_mfma_f32_16x16x32_f16(af[i], bf[j], acc[i][j], 0, 0, 0);
    }

    int r0 = lh * 4;
    bool isH = (n0 < 1024);
    #pragma unroll
    for (int i = 0; i < 4; i++)
        #pragma unroll
        for (int j = 0; j < 4; j++) {
            int gmb = m0 + 64*wm + 16*i + r0;
            int gn  = n0 + 64*wn + 16*j + lm;
            #pragma unroll
            for (int r = 0; r < 4; r++) {
                float v = acc[i][j][r];
                int gm = gmb + r;                 // m = b*512 + t
                if (isH) {
                    int tt = gm & 511, bb = gm >> 9;
                    size_t idx = (size_t)tt*65536 + (size_t)(bb>>4)*16384
                               + (size_t)(bb&15)*1024 + gn;   // b-major
                    Xh[idx] = (f16)(v + bh[gn]);
                } else {
                    float o = v + bo[gn - 1024];
                    size_t oidx = (size_t)gm*1024 + (gn - 1024);
                    if (useXo) Xo[oidx] = (f16)o;
                    else       Out[oidx] = o;
                }
            }
        }
}

// ---------- fused tree dispatch: vlevel (blockIdx.x < 8) + matrix squaring ----------
__global__ __launch_bounds__(256) void k_tree(
    const f16* __restrict__ M, const f16* __restrict__ Src, f16* __restrict__ Dst,
    int srcOff, int srcStep, int dstOff, int dstStep, int aBM,
    const f16* __restrict__ P, f16* __restrict__ Pout)
{
    __shared__ __align__(16) char pool[20480];
    int t = threadIdx.x;
    int l = t & 63, w = t >> 6;
    int wm = w >> 1, wn = w & 1;
    int lm = l & 15, lh = l >> 4;

    f32x4 acc[4][4];
    #pragma unroll
    for (int i = 0; i < 4; i++)
        #pragma unroll
        for (int j = 0; j < 4; j++) acc[i][j] = (f32x4){0.f,0.f,0.f,0.f};

    if (blockIdx.x < 8) {
        // ---------------- vlevel body ----------------
        f16* As = (f16*)pool;            // 8 KB
        f16* Bs = (f16*)(pool + 8192);   // 8 KB: [row][32] linear
        int m0 = blockIdx.y * 128;
        int n0 = blockIdx.x * 128;
        const size_t lgo = (size_t)(l >> 2) * 2048 + (size_t)(l & 3) * 16;
        const int kd0 = m0 >> 6;

        for (int kt = 0; kt < 32; ++kt) {
            __syncthreads();
            if (aBM) {
                size_t slab = (size_t)(srcOff + srcStep * (2*(kd0 + (w>>1))));
                const char* ga = (const char*)Src + slab*131072
                               + (size_t)(w&1)*65536 + (size_t)kt*64 + lgo;
                char* la = (char*)As + w * 2048;
                #pragma unroll
                for (int j = 0; j < 2; ++j)
                    __builtin_amdgcn_global_load_lds(
                        (const __attribute__((address_space(1))) void*)(ga + (size_t)j*32768),
                        (__attribute__((address_space(3))) void*)(la + j*1024), 16, 0, 0);
            } else {
                #pragma unroll
                for (int j = 0; j < 2; ++j) {
                    int ch  = w*2 + j;               // 0..7
                    int kdl = ch >> 2, bgc = ch & 3;
                    size_t slab = (size_t)(srcOff + srcStep * (2*(kd0 + kdl)));
                    const char* gsrc = (const char*)(Src + slab*65536
                                        + (size_t)bgc*16384 + (size_t)kt*512) + (size_t)l*16;
                    __builtin_amdgcn_global_load_lds(
                        (const __attribute__((address_space(1))) void*)gsrc,
                        (__attribute__((address_space(3))) void*)((char*)As + ch*1024), 16, 0, 0);
                }
            }
            {
                const char* gb = (const char*)(M + (size_t)(n0 + w*32) * 1024 + kt*32);
                char* lb = (char*)Bs + w * 2048;
                #pragma unroll
                for (int j = 0; j < 2; ++j)
                    __builtin_amdgcn_global_load_lds(
                        (const __attribute__((address_space(1))) void*)(gb + (size_t)j*32768 + lgo),
                        (__attribute__((address_space(3))) void*)(lb + j*1024), 16, 0, 0);
            }
            asm volatile("s_waitcnt vmcnt(0)" ::: "memory");
            __syncthreads();

            f16x8 af[4], bf[4];
            #pragma unroll
            for (int i = 0; i < 4; i++) {
                if (aBM) af[i] = *reinterpret_cast<const f16x8*>(As + (64*wm + 16*i + lm)*32 + 8*lh);
                else     af[i] = *reinterpret_cast<const f16x8*>(As + wm*2048 + i*512 + lh*128 + lm*8);
            }
            #pragma unroll
            for (int j = 0; j < 4; j++)
                bf[j] = *reinterpret_cast<const f16x8*>(Bs + (64*wn + 16*j + lm)*32 + 8*lh);
            #pragma unroll
            for (int i = 0; i < 4; i++)
                #pragma unroll
                for (int j = 0; j < 4; j++)
                    acc[i][j] = __builtin_amdgcn_mfma_f32_16x16x32_f16(af[i], bf[j], acc[i][j], 0, 0, 0);
        }

        int r0 = lh * 4;
        #pragma unroll
        for (int i = 0; i < 4; i++)
            #pragma unroll
            for (int j = 0; j < 4; j++) {
                int gmb = m0 + 64*wm + 16*i + r0;
                int gn  = n0 + 64*wn + 16*j + lm;
                #pragma unroll
                for (int r = 0; r < 4; r++) {
                    int gm = gmb + r;
                    int kd = gm >> 6, bb = gm & 63;
                    size_t aslab = (size_t)(srcOff + srcStep * (2*kd + 1));
                    float add;
                    if (aBM)
                        add = (float)Src[aslab*65536 + (size_t)(bb>>4)*16384
                                         + (size_t)(bb&15)*1024 + gn];
                    else
                        add = (float)Src[aslab*65536 + (size_t)(bb>>4)*16384
                                         + (size_t)(gn>>3)*128 + (size_t)(bb&15)*8 + (gn&7)];
                    size_t didx = (size_t)(dstOff + dstStep * kd)*65536
                                + (size_t)(bb>>4)*16384 + (size_t)(gn>>3)*128
                                + (size_t)(bb&15)*8 + (gn&7);          // Hs layout
                    Dst[didx] = (f16)(acc[i][j][r] + add);
                }
            }
    } else {
        // ---------------- sq body ----------------
        if (blockIdx.y >= 8) return;
        f16 (*As2)[40] = (f16(*)[40])pool;             // 10240 B
        f16 (*Bs2)[40] = (f16(*)[40])(pool + 10240);   // 10240 B
        int m0 = blockIdx.y * 128;
        int n0 = (blockIdx.x - 8) * 128;

        for (int kt = 0; kt < 32; ++kt) {
            __syncthreads();
            #pragma unroll
            for (int c = t; c < 512; c += 256) {       // A rows m, k-contig
                int row = c >> 2, q = c & 3;
                *reinterpret_cast<float4*>(&As2[row][q*8]) =
                    *reinterpret_cast<const float4*>(P + (size_t)(m0+row)*1024 + kt*32 + q*8);
            }
            #pragma unroll
            for (int c = t; c < 512; c += 256) {       // Bs[n][k] = P[k][n0+n]
                int r = c >> 4, q = c & 15;
                f16x8 v = *reinterpret_cast<const f16x8*>(P + (size_t)(kt*32 + r)*1024 + n0 + q*8);
                #pragma unroll
                for (int e = 0; e < 8; ++e) Bs2[q*8+e][r] = v[e];
            }
            __syncthreads();

            f16x8 af[4], bf[4];
            #pragma unroll
            for (int i = 0; i < 4; i++)
                af[i] = *reinterpret_cast<const f16x8*>(&As2[64*wm + 16*i + lm][8*lh]);
            #pragma unroll
            for (int j = 0; j < 4; j++)
                bf[j] = *reinterpret_cast<const f16x8*>(&Bs2[64*wn + 16*j + lm][8*lh]);
            #pragma unroll
            for (int i = 0; i < 4; i++)
                #pragma unroll
                for (int j = 0; j < 4; j++)
                    acc[i][j] = __builtin_amdgcn_mfma_f32_16x16x32_f16(af[i], bf[j], acc[i][j], 0, 0, 0);
        }

        int r0 = lh * 4;
        #pragma unroll
        for (int i = 0; i < 4; i++)
            #pragma unroll
            for (int j = 0; j < 4; j++) {
                int gmb = m0 + 64*wm + 16*i + r0;
                int gn  = n0 + 64*wn + 16*j + lm;
                #pragma unroll
                for (int r = 0; r < 4; r++)
                    Pout[(size_t)(gmb+r)*1024 + gn] = (f16)acc[i][j][r];
            }
    }
}

// ---------- flag-sync recurrence kernel (r13-verified; XV mode-conditional) ----------
__global__ void __launch_bounds__(256) __attribute__((amdgpu_waves_per_eu(1, 1)))
k_chain(
    const f16* __restrict__ W,        // [1024][1024] row-major (A or A16)
    const f16* __restrict__ U,        // u base (slab-packed)
    f16* __restrict__ Hs,
    unsigned int* __restrict__ flags,
    int nstep, int mode, int nch)
{
    int wg = blockIdx.x;
    int r_ = wg & 7, s_ = wg >> 3;
    int g, cg, p, bg;
    if (mode == 1) { g = r_ >> 1; cg = ((r_ & 1) << 3) | s_; p = 0;       bg = g;     }
    else           { g = 2*r_ + (s_ >> 4); cg = s_ & 15;     p = g >> 2;  bg = g & 3; }
    int w  = threadIdx.x >> 6;
    int l  = threadIdx.x & 63;
    int lm = l & 15, lh = l >> 4;
    int ccol = cg * 64 + w * 16 + lm;

    __shared__ f16 hbuf[2][16384];      // 64 KB double-buffered h slab
    __shared__ float lt[4][16][17];

    f16x8 bw[32];
    #pragma unroll
    for (int kt = 0; kt < 32; ++kt)
        bw[kt] = *reinterpret_cast<const f16x8*>(W + (size_t)ccol * 1024 + kt*32 + lh*8);
    #pragma unroll
    for (int kt = 0; kt < 32; ++kt)
        asm volatile("" : "+v"(bw[kt]));

    const int flagBase = g * 16;
    int b_ep = l & 15, cb_ep = l >> 4;
    int cblk = cg*8 + w*2 + cb_ep;

    for (int t = 0; t < nstep; ++t) {
        if (t > 0) {
            if (threadIdx.x < 16) {
                unsigned int tgt = (unsigned int)t;
                const unsigned int* fp = &flags[(flagBase + (int)threadIdx.x) * 8];
                while (__hip_atomic_load(fp, __ATOMIC_RELAXED, __HIP_MEMORY_SCOPE_AGENT) < tgt)
                    __builtin_amdgcn_s_sleep(1);
            }
            __syncthreads();
            asm volatile("" ::: "memory");
        }

        auto slabs = [&](int i, size_t& rS, size_t& wS, size_t& uS) {
            if (mode == 1) { rS = (size_t)(16*t); wS = rS + 16; uS = rS + 8; }
            else { int c = p*nch + i; rS = (size_t)(c*16 + t); wS = rS + 1; uS = rS; }
        };
        auto STAGE = [&](size_t rS, int buf) {
            const char* gsrc = (const char*)Hs + (rS*65536 + (size_t)bg*16384)*2
                             + (size_t)w*8192 + (size_t)l*16;
            char* ldst = (char*)&hbuf[buf][0] + (size_t)w*8192;
            #pragma unroll
            for (int q = 0; q < 8; ++q)
                __builtin_amdgcn_global_load_lds(
                    (const __attribute__((address_space(1))) void*)(gsrc + q*1024),
                    (__attribute__((address_space(3))) void*)(ldst + q*1024),
                    16, 0, 0);
        };
        auto XV = [&](size_t uS) -> f16x8 {
            f16x8 v = {};
            if (l < 32) {
                if (mode == 1)
                    v = *reinterpret_cast<const f16x8*>(
                        U + uS*65536 + (size_t)bg*16384 + (size_t)cblk*128 + b_ep*8);
                else
                    v = *reinterpret_cast<const f16x8*>(
                        U + uS*65536 + (size_t)bg*16384 + (size_t)b_ep*1024 + cblk*8);
            }
            return v;
        };

        // prologue: chunk 0 -> buf 0 (9 memops/wave)
        f16x8 xv0, xv1;
        {
            size_t rS, wS, uS; slabs(0, rS, wS, uS);
            STAGE(rS, 0);
            xv0 = XV(uS);
        }

        for (int i = 0; i < nch; ++i) {
            int nxt = i + 1;
            if (nxt < nch) {
                size_t rS, wS, uS; slabs(nxt, rS, wS, uS);
                STAGE(rS, nxt & 1);
                if (nxt & 1) xv1 = XV(uS); else xv0 = XV(uS);
                asm volatile("s_waitcnt vmcnt(9)" ::: "memory");
            } else {
                asm volatile("s_waitcnt vmcnt(0)" ::: "memory");
            }
            __syncthreads();

            const f16* cbuf = &hbuf[i & 1][0];
            f32x4 a0 = (f32x4){0.f,0.f,0.f,0.f};
            f32x4 a1 = (f32x4){0.f,0.f,0.f,0.f};
            #pragma unroll
            for (int kt = 0; kt < 32; ++kt) {
                f16x8 af = *reinterpret_cast<const f16x8*>(&cbuf[(size_t)(kt*4 + lh)*128 + lm*8]);
                if (kt & 1) a1 = __builtin_amdgcn_mfma_f32_16x16x32_f16(af, bw[kt], a1, 0, 0, 0);
                else        a0 = __builtin_amdgcn_mfma_f32_16x16x32_f16(af, bw[kt], a0, 0, 0, 0);
            }
            f32x4 acc = a0 + a1;

            #pragma unroll
            for (int r = 0; r < 4; ++r)
                lt[w][lh*4 + r][lm] = acc[r];
            // wave-private RAW through LDS (compiler inserts lgkmcnt)

            if (l < 32) {
                f16x8 xvc = (i & 1) ? xv1 : xv0;
                size_t rS, wS, uS; slabs(i, rS, wS, uS);
                f16x8 hv;
                #pragma unroll
                for (int e = 0; e < 8; ++e)
                    hv[e] = (f16)(lt[w][b_ep][cb_ep*8 + e] + (float)xvc[e]);
                f16* dst = Hs + wS*65536 + (size_t)bg*16384 + (size_t)cblk*128 + b_ep*8;
                i32x4 iv = __builtin_bit_cast(i32x4, hv);
                asm volatile("global_store_dwordx4 %0, %1, off sc0 sc1"
                             :: "v"(dst), "v"(iv) : "memory");
            }
            __syncthreads();   // all waves done reading buf[i&1] before it is restaged
        }

        asm volatile("s_waitcnt vmcnt(0)" ::: "memory");
        __syncthreads();
        if (threadIdx.x == 0) {
            unsigned int* fp = &flags[(flagBase + cg)*8];
            unsigned int val = (unsigned int)(t + 1);
            asm volatile("global_store_dword %0, %1, off sc0 sc1"
                         :: "v"(fp), "v"(val) : "memory");
        }
    }
}

// ---------- phase 3: output GEMM ----------
// useXo: Out = Xo + Hs@Wro^T (pure write). fallback: Out += Hs@Wro^T.
__global__ __launch_bounds__(256) void k_gemm2(
    const f16* __restrict__ Hs, const f16* __restrict__ Bm, float* __restrict__ Out,
    const f16* __restrict__ Xo, int useXo)
{
    __shared__ f16 As[4096];   // 8 KB: [ttloc2][bg4][kblk4][b16][e8]
    __shared__ f16 Bs[128*32]; // 8 KB
    int m0 = blockIdx.y * 128;          // m' = t*64 + b
    int n0 = blockIdx.x * 128;
    int t = threadIdx.x;
    int l = t & 63, w = t >> 6;
    int wm = w >> 1, wn = w & 1;
    int lm = l & 15, lh = l >> 4;

    f32x4 acc[4][4];
    #pragma unroll
    for (int i = 0; i < 4; i++)
        #pragma unroll
        for (int j = 0; j < 4; j++) acc[i][j] = (f32x4){0.f,0.f,0.f,0.f};

    const size_t lgo = (size_t)(l >> 2) * 2048 + (size_t)(l & 3) * 16;
    const int tt0 = m0 >> 6;

    for (int kt = 0; kt < 32; ++kt) {
        __syncthreads();
        {
            #pragma unroll
            for (int j = 0; j < 2; ++j) {
                int ch  = w*2 + j;               // 0..7
                int ttl = ch >> 2, bgc = ch & 3;
                const char* gsrc = (const char*)(Hs + (size_t)(tt0 + ttl)*65536
                                    + (size_t)bgc*16384 + (size_t)kt*512) + (size_t)l*16;
                __builtin_amdgcn_global_load_lds(
                    (const __attribute__((address_space(1))) void*)gsrc,
                    (__attribute__((address_space(3))) void*)((char*)As + ch*1024), 16, 0, 0);
            }
            const char* gb = (const char*)(Bm + (size_t)(n0 + w*32) * 1024 + kt*32);
            char* lb = (char*)Bs + w * 2048;
            #pragma unroll
            for (int j = 0; j < 2; ++j)
                __builtin_amdgcn_global_load_lds(
                    (const __attribute__((address_space(1))) void*)(gb + (size_t)j*32768 + lgo),
                    (__attribute__((address_space(3))) void*)(lb + j*1024), 16, 0, 0);
        }
        asm volatile("s_waitcnt vmcnt(0)" ::: "memory");
        __syncthreads();

        f16x8 af[4], bf[4];
        #pragma unroll
        for (int i = 0; i < 4; i++)
            af[i] = *reinterpret_cast<const f16x8*>(As + wm*2048 + i*512 + lh*128 + lm*8);
        #pragma unroll
        for (int j = 0; j < 4; j++)
            bf[j] = *reinterpret_cast<const f16x8*>(Bs + (64*wn + 16*j + lm)*32 + 8*lh);
        #pragma unroll
        for (int i = 0; i < 4; i++)
            #pragma unroll
            for (int j = 0; j < 4; j++)
                acc[i][j] = __builtin_amdgcn_mfma_f32_16x16x32_f16(af[i], bf[j], acc[i][j], 0, 0, 0);
    }

    int r0 = lh * 4;
    #pragma unroll
    for (int i = 0; i < 4; i++)
        #pragma unroll
        for (int j = 0; j < 4; j++) {
            int gmb = m0 + 64*wm + 16*i + r0;
            int gn  = n0 + 64*wn + 16*j + lm;
            #pragma unroll
            for (int r = 0; r < 4; r++) {
                int gm = gmb + r;               // m' = t*64 + b
                int bb = gm & 63, tt = gm >> 6;
                size_t o = ((size_t)bb*512 + tt)*1024 + gn;
                if (useXo) Out[o] = acc[i][j][r] + (float)Xo[o];
                else       Out[o] += acc[i][j][r];
            }
        }
}

// ---------- workspace layout (bytes) ----------
// [0, 4M)      Wx (gemm1); afterwards Pa @0, Pb @2M (A-power ping-pong)
// [4M, 8M)     Wr  (rows 0..1023 = A = Wrh, rows 1024..2047 = Wro)
// [8M, 72M)    Xh  [512 b-major slabs]
// [72M, 136M)  Hs  [512 Hs-layout slabs]; ALSO Xf pre-gemm1 (dead after);
//              then V1 -> slabs 1..256, V2 -> odd 257.., V3 -> 2+4m, V4 -> 8+16m
// [136M, +16K) flags u32[4096]: chain bank [0,512), fill bank [512,2560)
// [144M, 208M) Xo f16 [32768][1024]  (only if ws_size >= 208M)

extern "C" void kernel_launch(void* const* d_in, const int* in_sizes, int n_in,
                              void* d_out, int out_size, void* d_ws, size_t ws_size,
                              hipStream_t stream) {
    const float* X  = (const float*)d_in[0];
    const float* H0 = (const float*)d_in[1];
    const float* Wh = (const float*)d_in[2];
    const float* bh = (const float*)d_in[3];
    const float* Wo = (const float*)d_in[4];
    const float* bo = (const float*)d_in[5];
    float* Out = (float*)d_out;

    char* ws = (char*)d_ws;
    f16* Wx = (f16*)(ws);
    f16* Pa = (f16*)(ws);                               // aliases Wx (dead after gemm1)
    f16* Pb = (f16*)(ws + (size_t)2*1024*1024);
    f16* Wr = (f16*)(ws + (size_t)4*1024*1024);
    f16* Xh = (f16*)(ws + (size_t)8*1024*1024);
    f16* Hs = (f16*)(ws + (size_t)8*1024*1024 + (size_t)M_TOT*1024*2);
    f16* Xf = Hs;                                       // aliases Hs (dead until after gemm1)
    unsigned int* flags = (unsigned int*)(ws + (size_t)8*1024*1024 + (size_t)2*M_TOT*1024*2);

    const size_t XO_OFF = (size_t)144*1024*1024;
    int useXo = (ws_size >= XO_OFF + (size_t)M_TOT*1024*2) ? 1 : 0;
    f16* Xo = (f16*)(ws + XO_OFF);

    hipLaunchKernelGGL(k_prep, dim3(16384 + 2048), dim3(256), 0, stream, Wh, Wo, X, Wx, Wr, Xf);
    hipLaunchKernelGGL(k_gemm1, dim3(16, 256), dim3(256), 0, stream, Xf, Wx, bh, bo, Xh, Out, Xo, useXo);
    hipLaunchKernelGGL(k_init, dim3(48), dim3(256), 0, stream, H0, Hs, flags);  // after gemm1: Xf dead

    // fused tree: each dispatch = vlevel (8 x nx blocks) + squaring (8 x 8)
    hipLaunchKernelGGL(k_tree, dim3(16, 128), dim3(256), 0, stream, Wr, Xh, Hs, 0,1, 1,1,   1, Wr, Pa); // V1 + A2
    hipLaunchKernelGGL(k_tree, dim3(16, 64),  dim3(256), 0, stream, Pa, Hs, Hs, 1,1, 257,2,  0, Pa, Pb); // V2 + A4
    hipLaunchKernelGGL(k_tree, dim3(16, 32),  dim3(256), 0, stream, Pb, Hs, Hs, 257,2, 2,4,  0, Pb, Pa); // V3 + A8
    hipLaunchKernelGGL(k_tree, dim3(16, 16),  dim3(256), 0, stream, Pa, Hs, Hs, 2,4, 8,16,   0, Pa, Pb); // V4 + A16

    // chain: h_{16(t+1)} = A16 h_{16t} + v4_t   (31 steps, 64 WGs, flag bank 0)
    {
        int nstep = 31, mode = 1, nch = 1;
        void* args[] = { (void*)&Pb, (void*)&Hs, (void*)&Hs, (void*)&flags,
                         (void*)&nstep, (void*)&mode, (void*)&nch };
        if (hipLaunchCooperativeKernel((const void*)k_chain, dim3(64), dim3(256),
                                       args, 0, stream) != hipSuccess) {
            hipLaunchKernelGGL(k_chain, dim3(64), dim3(256), 0, stream,
                               Pb, Hs, Hs, flags, 31, 1, 1);
        }
    }

    // fill: h_{c*16+t+1} = A h_{c*16+t} + u(Xh b-major)  (15 steps, 256 WGs, bank 512)
    {
        unsigned int* flags2 = flags + 512;
        int nstep = 15, mode = 2, nch = 8;
        void* args[] = { (void*)&Wr, (void*)&Xh, (void*)&Hs, (void*)&flags2,
                         (void*)&nstep, (void*)&mode, (void*)&nch };
        if (hipLaunchCooperativeKernel((const void*)k_chain, dim3(256), dim3(256),
                                       args, 0, stream) != hipSuccess) {
            hipLaunchKernelGGL(k_chain, dim3(256), dim3(256), 0, stream,
                               Wr, Xh, Hs, flags2, 15, 2, 8);
        }
    }

    f16* Wro = Wr + (size_t)1024*1024;
    hipLaunchKernelGGL(k_gemm2, dim3(8, 256), dim3(256), 0, stream, Hs, Wro, Out, Xo, useXo);
}

// Round 19
// 985.806 us; speedup vs baseline: 1.0138x; 1.0138x over previous
//
#include <hip/hip_runtime.h>
#include <hip/hip_bf16.h>

// RNNLayer: B=64, T=512, D_IN=D_H=D_OUT=1024.
// h_{t+1} = A h_t + u_t  (A = Wrh, u_t = x_t@Wxh^T + bh);  o_t = x_t@Wxo^T + h_t@Wro^T + bo
// Scan decomposition (sequential depth 511 -> 31 + 15):
//   tree:  v1=A u+u', v2=A2 v1+v1', v3=A4 v2+v2', v4=A8 v3+v3'  (4 fused GEMM dispatches)
//   chain: h_{16(k+1)} = A16 h_{16k} + v4_k       (31 flag-sync steps, 64 WGs)
//   fill:  h_{16k+tau+1} = A h_{16k+tau} + u      (15 flag-sync steps, 256 WGs, nch=8)
// r18 -> r19: gemm1 epilogue rebuilt as LDS-transpose + wide stores. The old
// epilogue issued 64 scalar f16 stores/thread (issue-bound tail, 4x more
// epilogues than the 874-TF m97 reference at 4096^3). Now: bias-added f16 tile
// -> 34 KB LDS (overlays As/Bs post-barrier) -> each thread stores a 64-col
// row-half as 8x f16x8 (b-major Xh / flat Xo are row-contiguous). 8x fewer VM
// store instructions. All other kernels byte-identical to r18.

typedef _Float16 f16;
typedef _Float16 f16x8 __attribute__((ext_vector_type(8)));
typedef _Float16 f16x4 __attribute__((ext_vector_type(4)));
typedef float f32x4 __attribute__((ext_vector_type(4)));
typedef int i32x4 __attribute__((ext_vector_type(4)));

#define T_LEN 512
#define BATCH 64
#define M_TOT (BATCH * T_LEN)   // 32768

// Hs slab layout (per t): [bg 4][cblk 128][b 16][8] f16 = 65536 elems (128 KB)
// Xh slab layout (per t): [bg 4][b 16][col 1024]  f16 (b-major)
// Xo layout: [b][t][1024] f16 (same index space as Out)

// ---------- prep: stacked fp16 weights + X f32->f16 (fused) ----------
__global__ void k_prep(const float* __restrict__ Wh, const float* __restrict__ Wo,
                       const float* __restrict__ X,
                       f16* __restrict__ Wx, f16* __restrict__ Wr, f16* __restrict__ Xf) {
    int bid = blockIdx.x;
    if (bid < 16384) {
        size_t i = ((size_t)bid * 256 + threadIdx.x) * 8;
        float4 a = *reinterpret_cast<const float4*>(X + i);
        float4 b = *reinterpret_cast<const float4*>(X + i + 4);
        f16x8 v;
        v[0]=(f16)a.x; v[1]=(f16)a.y; v[2]=(f16)a.z; v[3]=(f16)a.w;
        v[4]=(f16)b.x; v[5]=(f16)b.y; v[6]=(f16)b.z; v[7]=(f16)b.w;
        *reinterpret_cast<f16x8*>(Xf + i) = v;
    } else {
        int n = bid - 16384;             // 0..2047
        int t4 = threadIdx.x * 4;        // 0..1020
        const float* src = (n < 1024) ? (Wh + (size_t)n * 2048)
                                      : (Wo + (size_t)(n - 1024) * 2048);
        float4 a = *reinterpret_cast<const float4*>(src + t4);
        float4 b = *reinterpret_cast<const float4*>(src + 1024 + t4);
        f16x4 va, vb;
        va[0]=(f16)a.x; va[1]=(f16)a.y; va[2]=(f16)a.z; va[3]=(f16)a.w;
        vb[0]=(f16)b.x; vb[1]=(f16)b.y; vb[2]=(f16)b.z; vb[3]=(f16)b.w;
        *reinterpret_cast<f16x4*>(Wx + (size_t)n*1024 + t4) = va;
        *reinterpret_cast<f16x4*>(Wr + (size_t)n*1024 + t4) = vb;
    }
}

// ---------- init: Hs[0] from H0 (packed) + zero both flag banks (fused) ----------
__global__ void k_init(const float* __restrict__ H0, f16* __restrict__ Hs,
                       unsigned int* __restrict__ flags) {
    int bid = blockIdx.x;
    if (bid < 32) {
        int tid = bid * 256 + threadIdx.x;   // 8192
        int b = tid >> 7, kb = tid & 127;
        float4 x0 = *reinterpret_cast<const float4*>(H0 + (size_t)b*1024 + kb*8);
        float4 x1 = *reinterpret_cast<const float4*>(H0 + (size_t)b*1024 + kb*8 + 4);
        f16x8 v;
        v[0]=(f16)x0.x; v[1]=(f16)x0.y; v[2]=(f16)x0.z; v[3]=(f16)x0.w;
        v[4]=(f16)x1.x; v[5]=(f16)x1.y; v[6]=(f16)x1.z; v[7]=(f16)x1.w;
        size_t idx = (size_t)(b >> 4)*16384 + (size_t)kb*128 + (size_t)(b & 15)*8;
        *reinterpret_cast<f16x8*>(Hs + idx) = v;
    } else {
        flags[(bid - 32) * 256 + threadIdx.x] = 0;   // 16 blocks -> 4096 u32 (16 KB)
    }
}

// ---------- phase 1: input projection GEMM (m97 structure, BK=32; r19 epilogue) ----------
// grid (16 n-tiles, 256 m-tiles). Epilogue: acc -> f16 LDS tile -> f16x8 stores.
__global__ __launch_bounds__(256) void k_gemm1(
    const f16* __restrict__ Af, const f16* __restrict__ Bm,
    const float* __restrict__ bh, const float* __restrict__ bo,
    f16* __restrict__ Xh, float* __restrict__ Out, f16* __restrict__ Xo, int useXo)
{
    __shared__ __align__(16) char pool[128*136*2];   // 34 KB; K-loop uses first 16 KB
    f16* As = (f16*)pool;            // 8 KB, linear [128][32]
    f16* Bs = (f16*)(pool + 8192);   // 8 KB
    f16* Cs = (f16*)pool;            // epilogue: [128][136] f16 (post-barrier overlay)
    int m0 = blockIdx.y * 128;
    int n0 = blockIdx.x * 128;
    int t = threadIdx.x;
    int l = t & 63, w = t >> 6;
    int wm = w >> 1, wn = w & 1;
    int lm = l & 15, lh = l >> 4;

    f32x4 acc[4][4];
    #pragma unroll
    for (int i = 0; i < 4; i++)
        #pragma unroll
        for (int j = 0; j < 4; j++) acc[i][j] = (f32x4){0.f,0.f,0.f,0.f};

    const size_t lgo = (size_t)(l >> 2) * 2048 + (size_t)(l & 3) * 16;

    for (int kt = 0; kt < 32; ++kt) {
        __syncthreads();
        {
            const char* ga = (const char*)(Af + (size_t)(m0 + w*32) * 1024 + kt*32);
            const char* gb = (const char*)(Bm + (size_t)(n0 + w*32) * 1024 + kt*32);
            char* la = (char*)As + w * 2048;
            char* lb = (char*)Bs + w * 2048;
            #pragma unroll
            for (int j = 0; j < 2; ++j) {
                __builtin_amdgcn_global_load_lds(
                    (const __attribute__((address_space(1))) void*)(ga + (size_t)j*32768 + lgo),
                    (__attribute__((address_space(3))) void*)(la + j*1024), 16, 0, 0);
                __builtin_amdgcn_global_load_lds(
                    (const __attribute__((address_space(1))) void*)(gb + (size_t)j*32768 + lgo),
                    (__attribute__((address_space(3))) void*)(lb + j*1024), 16, 0, 0);
            }
        }
        asm volatile("s_waitcnt vmcnt(0)" ::: "memory");
        __syncthreads();

        f16x8 af[4], bf[4];
        #pragma unroll
        for (int i = 0; i < 4; i++)
            af[i] = *reinterpret_cast<const f16x8*>(As + (64*wm + 16*i + lm)*32 + 8*lh);
        #pragma unroll
        for (int j = 0; j < 4; j++)
            bf[j] = *reinterpret_cast<const f16x8*>(Bs + (64*wn + 16*j + lm)*32 + 8*lh);
        #pragma unroll
        for (int i = 0; i < 4; i++)
            #pragma unroll
            for (int j = 0; j < 4; j++)
                acc[i][j] = __builtin_amdgcn_mfma_f32_16x16x32_f16(af[i], bf[j], acc[i][j], 0, 0, 0);
    }

    // ---- epilogue: LDS transpose + wide stores ----
    __syncthreads();    // all frag reads done; Cs overlays As/Bs
    bool isH = (n0 < 1024);
    int r0 = lh * 4;
    #pragma unroll
    for (int i = 0; i < 4; i++)
        #pragma unroll
        for (int j = 0; j < 4; j++) {
            int row = 64*wm + 16*i + r0;
            int col = 64*wn + 16*j + lm;
            float bias = isH ? bh[n0 + col] : bo[n0 - 1024 + col];
            #pragma unroll
            for (int r = 0; r < 4; r++)
                Cs[(size_t)(row + r)*136 + col] = (f16)(acc[i][j][r] + bias);
        }
    __syncthreads();

    {
        int row = t >> 1;                 // 0..127
        int cp  = (t & 1) * 64;           // column half
        int gm  = m0 + row;               // m = b*512 + t
        const f16* src = Cs + (size_t)row*136 + cp;
        if (isH) {
            int tt = gm & 511, bb = gm >> 9;
            f16* dst = Xh + (size_t)tt*65536 + (size_t)(bb>>4)*16384
                     + (size_t)(bb&15)*1024 + (n0 + cp);
            #pragma unroll
            for (int k = 0; k < 8; ++k)
                *reinterpret_cast<f16x8*>(dst + k*8) =
                    *reinterpret_cast<const f16x8*>(src + k*8);
        } else if (useXo) {
            f16* dst = Xo + (size_t)gm*1024 + (n0 - 1024 + cp);
            #pragma unroll
            for (int k = 0; k < 8; ++k)
                *reinterpret_cast<f16x8*>(dst + k*8) =
                    *reinterpret_cast<const f16x8*>(src + k*8);
        } else {
            float* dst = Out + (size_t)gm*1024 + (n0 - 1024 + cp);
            #pragma unroll
            for (int k = 0; k < 64; ++k)
                dst[k] = (float)src[k];
        }
    }
}

// ---------- fused tree dispatch: vlevel (blockIdx.x < 8) + matrix squaring ----------
__global__ __launch_bounds__(256) void k_tree(
    const f16* __restrict__ M, const f16* __restrict__ Src, f16* __restrict__ Dst,
    int srcOff, int srcStep, int dstOff, int dstStep, int aBM,
    const f16* __restrict__ P, f16* __restrict__ Pout)
{
    __shared__ __align__(16) char pool[20480];
    int t = threadIdx.x;
    int l = t & 63, w = t >> 6;
    int wm = w >> 1, wn = w & 1;
    int lm = l & 15, lh = l >> 4;

    f32x4 acc[4][4];
    #pragma unroll
    for (int i = 0; i < 4; i++)
        #pragma unroll
        for (int j = 0; j < 4; j++) acc[i][j] = (f32x4){0.f,0.f,0.f,0.f};

    if (blockIdx.x < 8) {
        // ---------------- vlevel body ----------------
        f16* As = (f16*)pool;            // 8 KB
        f16* Bs = (f16*)(pool + 8192);   // 8 KB: [row][32] linear
        int m0 = blockIdx.y * 128;
        int n0 = blockIdx.x * 128;
        const size_t lgo = (size_t)(l >> 2) * 2048 + (size_t)(l & 3) * 16;
        const int kd0 = m0 >> 6;

        for (int kt = 0; kt < 32; ++kt) {
            __syncthreads();
            if (aBM) {
                size_t slab = (size_t)(srcOff + srcStep * (2*(kd0 + (w>>1))));
                const char* ga = (const char*)Src + slab*131072
                               + (size_t)(w&1)*65536 + (size_t)kt*64 + lgo;
                char* la = (char*)As + w * 2048;
                #pragma unroll
                for (int j = 0; j < 2; ++j)
                    __builtin_amdgcn_global_load_lds(
                        (const __attribute__((address_space(1))) void*)(ga + (size_t)j*32768),
                        (__attribute__((address_space(3))) void*)(la + j*1024), 16, 0, 0);
            } else {
                #pragma unroll
                for (int j = 0; j < 2; ++j) {
                    int ch  = w*2 + j;               // 0..7
                    int kdl = ch >> 2, bgc = ch & 3;
                    size_t slab = (size_t)(srcOff + srcStep * (2*(kd0 + kdl)));
                    const char* gsrc = (const char*)(Src + slab*65536
                                        + (size_t)bgc*16384 + (size_t)kt*512) + (size_t)l*16;
                    __builtin_amdgcn_global_load_lds(
                        (const __attribute__((address_space(1))) void*)gsrc,
                        (__attribute__((address_space(3))) void*)((char*)As + ch*1024), 16, 0, 0);
                }
            }
            {
                const char* gb = (const char*)(M + (size_t)(n0 + w*32) * 1024 + kt*32);
                char* lb = (char*)Bs + w * 2048;
                #pragma unroll
                for (int j = 0; j < 2; ++j)
                    __builtin_amdgcn_global_load_lds(
                        (const __attribute__((address_space(1))) void*)(gb + (size_t)j*32768 + lgo),
                        (__attribute__((address_space(3))) void*)(lb + j*1024), 16, 0, 0);
            }
            asm volatile("s_waitcnt vmcnt(0)" ::: "memory");
            __syncthreads();

            f16x8 af[4], bf[4];
            #pragma unroll
            for (int i = 0; i < 4; i++) {
                if (aBM) af[i] = *reinterpret_cast<const f16x8*>(As + (64*wm + 16*i + lm)*32 + 8*lh);
                else     af[i] = *reinterpret_cast<const f16x8*>(As + wm*2048 + i*512 + lh*128 + lm*8);
            }
            #pragma unroll
            for (int j = 0; j < 4; j++)
                bf[j] = *reinterpret_cast<const f16x8*>(Bs + (64*wn + 16*j + lm)*32 + 8*lh);
            #pragma unroll
            for (int i = 0; i < 4; i++)
                #pragma unroll
                for (int j = 0; j < 4; j++)
                    acc[i][j] = __builtin_amdgcn_mfma_f32_16x16x32_f16(af[i], bf[j], acc[i][j], 0, 0, 0);
        }

        int r0 = lh * 4;
        #pragma unroll
        for (int i = 0; i < 4; i++)
            #pragma unroll
            for (int j = 0; j < 4; j++) {
                int gmb = m0 + 64*wm + 16*i + r0;
                int gn  = n0 + 64*wn + 16*j + lm;
                #pragma unroll
                for (int r = 0; r < 4; r++) {
                    int gm = gmb + r;
                    int kd = gm >> 6, bb = gm & 63;
                    size_t aslab = (size_t)(srcOff + srcStep * (2*kd + 1));
                    float add;
                    if (aBM)
                        add = (float)Src[aslab*65536 + (size_t)(bb>>4)*16384
                                         + (size_t)(bb&15)*1024 + gn];
                    else
                        add = (float)Src[aslab*65536 + (size_t)(bb>>4)*16384
                                         + (size_t)(gn>>3)*128 + (size_t)(bb&15)*8 + (gn&7)];
                    size_t didx = (size_t)(dstOff + dstStep * kd)*65536
                                + (size_t)(bb>>4)*16384 + (size_t)(gn>>3)*128
                                + (size_t)(bb&15)*8 + (gn&7);          // Hs layout
                    Dst[didx] = (f16)(acc[i][j][r] + add);
                }
            }
    } else {
        // ---------------- sq body ----------------
        if (blockIdx.y >= 8) return;
        f16 (*As2)[40] = (f16(*)[40])pool;             // 10240 B
        f16 (*Bs2)[40] = (f16(*)[40])(pool + 10240);   // 10240 B
        int m0 = blockIdx.y * 128;
        int n0 = (blockIdx.x - 8) * 128;

        for (int kt = 0; kt < 32; ++kt) {
            __syncthreads();
            #pragma unroll
            for (int c = t; c < 512; c += 256) {       // A rows m, k-contig
                int row = c >> 2, q = c & 3;
                *reinterpret_cast<float4*>(&As2[row][q*8]) =
                    *reinterpret_cast<const float4*>(P + (size_t)(m0+row)*1024 + kt*32 + q*8);
            }
            #pragma unroll
            for (int c = t; c < 512; c += 256) {       // Bs[n][k] = P[k][n0+n]
                int r = c >> 4, q = c & 15;
                f16x8 v = *reinterpret_cast<const f16x8*>(P + (size_t)(kt*32 + r)*1024 + n0 + q*8);
                #pragma unroll
                for (int e = 0; e < 8; ++e) Bs2[q*8+e][r] = v[e];
            }
            __syncthreads();

            f16x8 af[4], bf[4];
            #pragma unroll
            for (int i = 0; i < 4; i++)
                af[i] = *reinterpret_cast<const f16x8*>(&As2[64*wm + 16*i + lm][8*lh]);
            #pragma unroll
            for (int j = 0; j < 4; j++)
                bf[j] = *reinterpret_cast<const f16x8*>(&Bs2[64*wn + 16*j + lm][8*lh]);
            #pragma unroll
            for (int i = 0; i < 4; i++)
                #pragma unroll
                for (int j = 0; j < 4; j++)
                    acc[i][j] = __builtin_amdgcn_mfma_f32_16x16x32_f16(af[i], bf[j], acc[i][j], 0, 0, 0);
        }

        int r0 = lh * 4;
        #pragma unroll
        for (int i = 0; i < 4; i++)
            #pragma unroll
            for (int j = 0; j < 4; j++) {
                int gmb = m0 + 64*wm + 16*i + r0;
                int gn  = n0 + 64*wn + 16*j + lm;
                #pragma unroll
                for (int r = 0; r < 4; r++)
                    Pout[(size_t)(gmb+r)*1024 + gn] = (f16)acc[i][j][r];
            }
    }
}

// ---------- flag-sync recurrence kernel (r13-verified; XV mode-conditional) ----------
__global__ void __launch_bounds__(256) __attribute__((amdgpu_waves_per_eu(1, 1)))
k_chain(
    const f16* __restrict__ W,        // [1024][1024] row-major (A or A16)
    const f16* __restrict__ U,        // u base (slab-packed)
    f16* __restrict__ Hs,
    unsigned int* __restrict__ flags,
    int nstep, int mode, int nch)
{
    int wg = blockIdx.x;
    int r_ = wg & 7, s_ = wg >> 3;
    int g, cg, p, bg;
    if (mode == 1) { g = r_ >> 1; cg = ((r_ & 1) << 3) | s_; p = 0;       bg = g;     }
    else           { g = 2*r_ + (s_ >> 4); cg = s_ & 15;     p = g >> 2;  bg = g & 3; }
    int w  = threadIdx.x >> 6;
    int l  = threadIdx.x & 63;
    int lm = l & 15, lh = l >> 4;
    int ccol = cg * 64 + w * 16 + lm;

    __shared__ f16 hbuf[2][16384];      // 64 KB double-buffered h slab
    __shared__ float lt[4][16][17];

    f16x8 bw[32];
    #pragma unroll
    for (int kt = 0; kt < 32; ++kt)
        bw[kt] = *reinterpret_cast<const f16x8*>(W + (size_t)ccol * 1024 + kt*32 + lh*8);
    #pragma unroll
    for (int kt = 0; kt < 32; ++kt)
        asm volatile("" : "+v"(bw[kt]));

    const int flagBase = g * 16;
    int b_ep = l & 15, cb_ep = l >> 4;
    int cblk = cg*8 + w*2 + cb_ep;

    for (int t = 0; t < nstep; ++t) {
        if (t > 0) {
            if (threadIdx.x < 16) {
                unsigned int tgt = (unsigned int)t;
                const unsigned int* fp = &flags[(flagBase + (int)threadIdx.x) * 8];
                while (__hip_atomic_load(fp, __ATOMIC_RELAXED, __HIP_MEMORY_SCOPE_AGENT) < tgt)
                    __builtin_amdgcn_s_sleep(1);
            }
            __syncthreads();
            asm volatile("" ::: "memory");
        }

        auto slabs = [&](int i, size_t& rS, size_t& wS, size_t& uS) {
            if (mode == 1) { rS = (size_t)(16*t); wS = rS + 16; uS = rS + 8; }
            else { int c = p*nch + i; rS = (size_t)(c*16 + t); wS = rS + 1; uS = rS; }
        };
        auto STAGE = [&](size_t rS, int buf) {
            const char* gsrc = (const char*)Hs + (rS*65536 + (size_t)bg*16384)*2
                             + (size_t)w*8192 + (size_t)l*16;
            char* ldst = (char*)&hbuf[buf][0] + (size_t)w*8192;
            #pragma unroll
            for (int q = 0; q < 8; ++q)
                __builtin_amdgcn_global_load_lds(
                    (const __attribute__((address_space(1))) void*)(gsrc + q*1024),
                    (__attribute__((address_space(3))) void*)(ldst + q*1024),
                    16, 0, 0);
        };
        auto XV = [&](size_t uS) -> f16x8 {
            f16x8 v = {};
            if (l < 32) {
                if (mode == 1)
                    v = *reinterpret_cast<const f16x8*>(
                        U + uS*65536 + (size_t)bg*16384 + (size_t)cblk*128 + b_ep*8);
                else
                    v = *reinterpret_cast<const f16x8*>(
                        U + uS*65536 + (size_t)bg*16384 + (size_t)b_ep*1024 + cblk*8);
            }
            return v;
        };

        // prologue: chunk 0 -> buf 0 (9 memops/wave)
        f16x8 xv0, xv1;
        {
            size_t rS, wS, uS; slabs(0, rS, wS, uS);
            STAGE(rS, 0);
            xv0 = XV(uS);
        }

        for (int i = 0; i < nch; ++i) {
            int nxt = i + 1;
            if (nxt < nch) {
                size_t rS, wS, uS; slabs(nxt, rS, wS, uS);
                STAGE(rS, nxt & 1);
                if (nxt & 1) xv1 = XV(uS); else xv0 = XV(uS);
                asm volatile("s_waitcnt vmcnt(9)" ::: "memory");
            } else {
                asm volatile("s_waitcnt vmcnt(0)" ::: "memory");
            }
            __syncthreads();

            const f16* cbuf = &hbuf[i & 1][0];
            f32x4 a0 = (f32x4){0.f,0.f,0.f,0.f};
            f32x4 a1 = (f32x4){0.f,0.f,0.f,0.f};
            #pragma unroll
            for (int kt = 0; kt < 32; ++kt) {
                f16x8 af = *reinterpret_cast<const f16x8*>(&cbuf[(size_t)(kt*4 + lh)*128 + lm*8]);
                if (kt & 1) a1 = __builtin_amdgcn_mfma_f32_16x16x32_f16(af, bw[kt], a1, 0, 0, 0);
                else        a0 = __builtin_amdgcn_mfma_f32_16x16x32_f16(af, bw[kt], a0, 0, 0, 0);
            }
            f32x4 acc = a0 + a1;

            #pragma unroll
            for (int r = 0; r < 4; ++r)
                lt[w][lh*4 + r][lm] = acc[r];
            // wave-private RAW through LDS (compiler inserts lgkmcnt)

            if (l < 32) {
                f16x8 xvc = (i & 1) ? xv1 : xv0;
                size_t rS, wS, uS; slabs(i, rS, wS, uS);
                f16x8 hv;
                #pragma unroll
                for (int e = 0; e < 8; ++e)
                    hv[e] = (f16)(lt[w][b_ep][cb_ep*8 + e] + (float)xvc[e]);
                f16* dst = Hs + wS*65536 + (size_t)bg*16384 + (size_t)cblk*128 + b_ep*8;
                i32x4 iv = __builtin_bit_cast(i32x4, hv);
                asm volatile("global_store_dwordx4 %0, %1, off sc0 sc1"
                             :: "v"(dst), "v"(iv) : "memory");
            }
            __syncthreads();   // all waves done reading buf[i&1] before it is restaged
        }

        asm volatile("s_waitcnt vmcnt(0)" ::: "memory");
        __syncthreads();
        if (threadIdx.x == 0) {
            unsigned int* fp = &flags[(flagBase + cg)*8];
            unsigned int val = (unsigned int)(t + 1);
            asm volatile("global_store_dword %0, %1, off sc0 sc1"
                         :: "v"(fp), "v"(val) : "memory");
        }
    }
}

// ---------- phase 3: output GEMM ----------
// useXo: Out = Xo + Hs@Wro^T (pure write). fallback: Out += Hs@Wro^T.
__global__ __launch_bounds__(256) void k_gemm2(
    const f16* __restrict__ Hs, const f16* __restrict__ Bm, float* __restrict__ Out,
    const f16* __restrict__ Xo, int useXo)
{
    __shared__ f16 As[4096];   // 8 KB: [ttloc2][bg4][kblk4][b16][e8]
    __shared__ f16 Bs[128*32]; // 8 KB
    int m0 = blockIdx.y * 128;          // m' = t*64 + b
    int n0 = blockIdx.x * 128;
    int t = threadIdx.x;
    int l = t & 63, w = t >> 6;
    int wm = w >> 1, wn = w & 1;
    int lm = l & 15, lh = l >> 4;

    f32x4 acc[4][4];
    #pragma unroll
    for (int i = 0; i < 4; i++)
        #pragma unroll
        for (int j = 0; j < 4; j++) acc[i][j] = (f32x4){0.f,0.f,0.f,0.f};

    const size_t lgo = (size_t)(l >> 2) * 2048 + (size_t)(l & 3) * 16;
    const int tt0 = m0 >> 6;

    for (int kt = 0; kt < 32; ++kt) {
        __syncthreads();
        {
            #pragma unroll
            for (int j = 0; j < 2; ++j) {
                int ch  = w*2 + j;               // 0..7
                int ttl = ch >> 2, bgc = ch & 3;
                const char* gsrc = (const char*)(Hs + (size_t)(tt0 + ttl)*65536
                                    + (size_t)bgc*16384 + (size_t)kt*512) + (size_t)l*16;
                __builtin_amdgcn_global_load_lds(
                    (const __attribute__((address_space(1))) void*)gsrc,
                    (__attribute__((address_space(3))) void*)((char*)As + ch*1024), 16, 0, 0);
            }
            const char* gb = (const char*)(Bm + (size_t)(n0 + w*32) * 1024 + kt*32);
            char* lb = (char*)Bs + w * 2048;
            #pragma unroll
            for (int j = 0; j < 2; ++j)
                __builtin_amdgcn_global_load_lds(
                    (const __attribute__((address_space(1))) void*)(gb + (size_t)j*32768 + lgo),
                    (__attribute__((address_space(3))) void*)(lb + j*1024), 16, 0, 0);
        }
        asm volatile("s_waitcnt vmcnt(0)" ::: "memory");
        __syncthreads();

        f16x8 af[4], bf[4];
        #pragma unroll
        for (int i = 0; i < 4; i++)
            af[i] = *reinterpret_cast<const f16x8*>(As + wm*2048 + i*512 + lh*128 + lm*8);
        #pragma unroll
        for (int j = 0; j < 4; j++)
            bf[j] = *reinterpret_cast<const f16x8*>(Bs + (64*wn + 16*j + lm)*32 + 8*lh);
        #pragma unroll
        for (int i = 0; i < 4; i++)
            #pragma unroll
            for (int j = 0; j < 4; j++)
                acc[i][j] = __builtin_amdgcn_mfma_f32_16x16x32_f16(af[i], bf[j], acc[i][j], 0, 0, 0);
    }

    int r0 = lh * 4;
    #pragma unroll
    for (int i = 0; i < 4; i++)
        #pragma unroll
        for (int j = 0; j < 4; j++) {
            int gmb = m0 + 64*wm + 16*i + r0;
            int gn  = n0 + 64*wn + 16*j + lm;
            #pragma unroll
            for (int r = 0; r < 4; r++) {
                int gm = gmb + r;               // m' = t*64 + b
                int bb = gm & 63, tt = gm >> 6;
                size_t o = ((size_t)bb*512 + tt)*1024 + gn;
                if (useXo) Out[o] = acc[i][j][r] + (float)Xo[o];
                else       Out[o] += acc[i][j][r];
            }
        }
}

// ---------- workspace layout (bytes) ----------
// [0, 4M)      Wx (gemm1); afterwards Pa @0, Pb @2M (A-power ping-pong)
// [4M, 8M)     Wr  (rows 0..1023 = A = Wrh, rows 1024..2047 = Wro)
// [8M, 72M)    Xh  [512 b-major slabs]
// [72M, 136M)  Hs  [512 Hs-layout slabs]; ALSO Xf pre-gemm1 (dead after);
//              then V1 -> slabs 1..256, V2 -> odd 257.., V3 -> 2+4m, V4 -> 8+16m
// [136M, +16K) flags u32[4096]: chain bank [0,512), fill bank [512,2560)
// [144M, 208M) Xo f16 [32768][1024]  (only if ws_size >= 208M)

extern "C" void kernel_launch(void* const* d_in, const int* in_sizes, int n_in,
                              void* d_out, int out_size, void* d_ws, size_t ws_size,
                              hipStream_t stream) {
    const float* X  = (const float*)d_in[0];
    const float* H0 = (const float*)d_in[1];
    const float* Wh = (const float*)d_in[2];
    const float* bh = (const float*)d_in[3];
    const float* Wo = (const float*)d_in[4];
    const float* bo = (const float*)d_in[5];
    float* Out = (float*)d_out;

    char* ws = (char*)d_ws;
    f16* Wx = (f16*)(ws);
    f16* Pa = (f16*)(ws);                               // aliases Wx (dead after gemm1)
    f16* Pb = (f16*)(ws + (size_t)2*1024*1024);
    f16* Wr = (f16*)(ws + (size_t)4*1024*1024);
    f16* Xh = (f16*)(ws + (size_t)8*1024*1024);
    f16* Hs = (f16*)(ws + (size_t)8*1024*1024 + (size_t)M_TOT*1024*2);
    f16* Xf = Hs;                                       // aliases Hs (dead until after gemm1)
    unsigned int* flags = (unsigned int*)(ws + (size_t)8*1024*1024 + (size_t)2*M_TOT*1024*2);

    const size_t XO_OFF = (size_t)144*1024*1024;
    int useXo = (ws_size >= XO_OFF + (size_t)M_TOT*1024*2) ? 1 : 0;
    f16* Xo = (f16*)(ws + XO_OFF);

    hipLaunchKernelGGL(k_prep, dim3(16384 + 2048), dim3(256), 0, stream, Wh, Wo, X, Wx, Wr, Xf);
    hipLaunchKernelGGL(k_gemm1, dim3(16, 256), dim3(256), 0, stream, Xf, Wx, bh, bo, Xh, Out, Xo, useXo);
    hipLaunchKernelGGL(k_init, dim3(48), dim3(256), 0, stream, H0, Hs, flags);  // after gemm1: Xf dead

    // fused tree: each dispatch = vlevel (8 x nx blocks) + squaring (8 x 8)
    hipLaunchKernelGGL(k_tree, dim3(16, 128), dim3(256), 0, stream, Wr, Xh, Hs, 0,1, 1,1,   1, Wr, Pa); // V1 + A2
    hipLaunchKernelGGL(k_tree, dim3(16, 64),  dim3(256), 0, stream, Pa, Hs, Hs, 1,1, 257,2,  0, Pa, Pb); // V2 + A4
    hipLaunchKernelGGL(k_tree, dim3(16, 32),  dim3(256), 0, stream, Pb, Hs, Hs, 257,2, 2,4,  0, Pb, Pa); // V3 + A8
    hipLaunchKernelGGL(k_tree, dim3(16, 16),  dim3(256), 0, stream, Pa, Hs, Hs, 2,4, 8,16,   0, Pa, Pb); // V4 + A16

    // chain: h_{16(t+1)} = A16 h_{16t} + v4_t   (31 steps, 64 WGs, flag bank 0)
    {
        int nstep = 31, mode = 1, nch = 1;
        void* args[] = { (void*)&Pb, (void*)&Hs, (void*)&Hs, (void*)&flags,
                         (void*)&nstep, (void*)&mode, (void*)&nch };
        if (hipLaunchCooperativeKernel((const void*)k_chain, dim3(64), dim3(256),
                                       args, 0, stream) != hipSuccess) {
            hipLaunchKernelGGL(k_chain, dim3(64), dim3(256), 0, stream,
                               Pb, Hs, Hs, flags, 31, 1, 1);
        }
    }

    // fill: h_{c*16+t+1} = A h_{c*16+t} + u(Xh b-major)  (15 steps, 256 WGs, bank 512)
    {
        unsigned int* flags2 = flags + 512;
        int nstep = 15, mode = 2, nch = 8;
        void* args[] = { (void*)&Wr, (void*)&Xh, (void*)&Hs, (void*)&flags2,
                         (void*)&nstep, (void*)&mode, (void*)&nch };
        if (hipLaunchCooperativeKernel((const void*)k_chain, dim3(256), dim3(256),
                                       args, 0, stream) != hipSuccess) {
            hipLaunchKernelGGL(k_chain, dim3(256), dim3(256), 0, stream,
                               Wr, Xh, Hs, flags2, 15, 2, 8);
        }
    }

    f16* Wro = Wr + (size_t)1024*1024;
    hipLaunchKernelGGL(k_gemm2, dim3(8, 256), dim3(256), 0, stream, Hs, Wro, Out, Xo, useXo);
}

// Round 20
// 975.418 us; speedup vs baseline: 1.0246x; 1.0107x over previous
//
#include <hip/hip_runtime.h>
#include <hip/hip_bf16.h>

// RNNLayer: B=64, T=512, D_IN=D_H=D_OUT=1024.
// h_{t+1} = A h_t + u_t  (A = Wrh, u_t = x_t@Wxh^T + bh);  o_t = x_t@Wxo^T + h_t@Wro^T + bo
// Scan decomposition (sequential depth 511 -> 31 + 15):
//   tree:  v1=A u+u', v2=A2 v1+v1', v3=A4 v2+v2', v4=A8 v3+v3'  (4 fused GEMM dispatches)
//   chain: h_{16(k+1)} = A16 h_{16k} + v4_k       (31 flag-sync steps, 64 WGs)
//   fill:  h_{16k+tau+1} = A h_{16k+tau} + u      (15 flag-sync steps, 256 WGs, nch=8)
// r19 -> r20: port the r19 epilogue lever (LDS transpose + wide stores) to
// k_tree's vlevel and k_gemm2. Two-pass f32 transpose (Cf[64][136], 34.8 KB,
// overlays As/Bs post-barrier; pass p = wm==p half-tile) -> per-thread wide
// f16x8/float4 ops, 16x fewer VM instructions. f32 passes through LDS exactly:
// numerics bit-identical. K-loops/staging/chain/fill/gemm1 byte-identical r19.

typedef _Float16 f16;
typedef _Float16 f16x8 __attribute__((ext_vector_type(8)));
typedef _Float16 f16x4 __attribute__((ext_vector_type(4)));
typedef float f32x4 __attribute__((ext_vector_type(4)));
typedef int i32x4 __attribute__((ext_vector_type(4)));

#define T_LEN 512
#define BATCH 64
#define M_TOT (BATCH * T_LEN)   // 32768

// Hs slab layout (per t): [bg 4][cblk 128][b 16][8] f16 = 65536 elems (128 KB)
// Xh slab layout (per t): [bg 4][b 16][col 1024]  f16 (b-major)
// Xo layout: [b][t][1024] f16 (same index space as Out)

// ---------- prep: stacked fp16 weights + X f32->f16 (fused) ----------
__global__ void k_prep(const float* __restrict__ Wh, const float* __restrict__ Wo,
                       const float* __restrict__ X,
                       f16* __restrict__ Wx, f16* __restrict__ Wr, f16* __restrict__ Xf) {
    int bid = blockIdx.x;
    if (bid < 16384) {
        size_t i = ((size_t)bid * 256 + threadIdx.x) * 8;
        float4 a = *reinterpret_cast<const float4*>(X + i);
        float4 b = *reinterpret_cast<const float4*>(X + i + 4);
        f16x8 v;
        v[0]=(f16)a.x; v[1]=(f16)a.y; v[2]=(f16)a.z; v[3]=(f16)a.w;
        v[4]=(f16)b.x; v[5]=(f16)b.y; v[6]=(f16)b.z; v[7]=(f16)b.w;
        *reinterpret_cast<f16x8*>(Xf + i) = v;
    } else {
        int n = bid - 16384;             // 0..2047
        int t4 = threadIdx.x * 4;        // 0..1020
        const float* src = (n < 1024) ? (Wh + (size_t)n * 2048)
                                      : (Wo + (size_t)(n - 1024) * 2048);
        float4 a = *reinterpret_cast<const float4*>(src + t4);
        float4 b = *reinterpret_cast<const float4*>(src + 1024 + t4);
        f16x4 va, vb;
        va[0]=(f16)a.x; va[1]=(f16)a.y; va[2]=(f16)a.z; va[3]=(f16)a.w;
        vb[0]=(f16)b.x; vb[1]=(f16)b.y; vb[2]=(f16)b.z; vb[3]=(f16)b.w;
        *reinterpret_cast<f16x4*>(Wx + (size_t)n*1024 + t4) = va;
        *reinterpret_cast<f16x4*>(Wr + (size_t)n*1024 + t4) = vb;
    }
}

// ---------- init: Hs[0] from H0 (packed) + zero both flag banks (fused) ----------
__global__ void k_init(const float* __restrict__ H0, f16* __restrict__ Hs,
                       unsigned int* __restrict__ flags) {
    int bid = blockIdx.x;
    if (bid < 32) {
        int tid = bid * 256 + threadIdx.x;   // 8192
        int b = tid >> 7, kb = tid & 127;
        float4 x0 = *reinterpret_cast<const float4*>(H0 + (size_t)b*1024 + kb*8);
        float4 x1 = *reinterpret_cast<const float4*>(H0 + (size_t)b*1024 + kb*8 + 4);
        f16x8 v;
        v[0]=(f16)x0.x; v[1]=(f16)x0.y; v[2]=(f16)x0.z; v[3]=(f16)x0.w;
        v[4]=(f16)x1.x; v[5]=(f16)x1.y; v[6]=(f16)x1.z; v[7]=(f16)x1.w;
        size_t idx = (size_t)(b >> 4)*16384 + (size_t)kb*128 + (size_t)(b & 15)*8;
        *reinterpret_cast<f16x8*>(Hs + idx) = v;
    } else {
        flags[(bid - 32) * 256 + threadIdx.x] = 0;   // 16 blocks -> 4096 u32 (16 KB)
    }
}

// ---------- phase 1: input projection GEMM (m97 structure, BK=32; r19 epilogue) ----------
__global__ __launch_bounds__(256) void k_gemm1(
    const f16* __restrict__ Af, const f16* __restrict__ Bm,
    const float* __restrict__ bh, const float* __restrict__ bo,
    f16* __restrict__ Xh, float* __restrict__ Out, f16* __restrict__ Xo, int useXo)
{
    __shared__ __align__(16) char pool[128*136*2];   // 34 KB; K-loop uses first 16 KB
    f16* As = (f16*)pool;            // 8 KB, linear [128][32]
    f16* Bs = (f16*)(pool + 8192);   // 8 KB
    f16* Cs = (f16*)pool;            // epilogue: [128][136] f16 (post-barrier overlay)
    int m0 = blockIdx.y * 128;
    int n0 = blockIdx.x * 128;
    int t = threadIdx.x;
    int l = t & 63, w = t >> 6;
    int wm = w >> 1, wn = w & 1;
    int lm = l & 15, lh = l >> 4;

    f32x4 acc[4][4];
    #pragma unroll
    for (int i = 0; i < 4; i++)
        #pragma unroll
        for (int j = 0; j < 4; j++) acc[i][j] = (f32x4){0.f,0.f,0.f,0.f};

    const size_t lgo = (size_t)(l >> 2) * 2048 + (size_t)(l & 3) * 16;

    for (int kt = 0; kt < 32; ++kt) {
        __syncthreads();
        {
            const char* ga = (const char*)(Af + (size_t)(m0 + w*32) * 1024 + kt*32);
            const char* gb = (const char*)(Bm + (size_t)(n0 + w*32) * 1024 + kt*32);
            char* la = (char*)As + w * 2048;
            char* lb = (char*)Bs + w * 2048;
            #pragma unroll
            for (int j = 0; j < 2; ++j) {
                __builtin_amdgcn_global_load_lds(
                    (const __attribute__((address_space(1))) void*)(ga + (size_t)j*32768 + lgo),
                    (__attribute__((address_space(3))) void*)(la + j*1024), 16, 0, 0);
                __builtin_amdgcn_global_load_lds(
                    (const __attribute__((address_space(1))) void*)(gb + (size_t)j*32768 + lgo),
                    (__attribute__((address_space(3))) void*)(lb + j*1024), 16, 0, 0);
            }
        }
        asm volatile("s_waitcnt vmcnt(0)" ::: "memory");
        __syncthreads();

        f16x8 af[4], bf[4];
        #pragma unroll
        for (int i = 0; i < 4; i++)
            af[i] = *reinterpret_cast<const f16x8*>(As + (64*wm + 16*i + lm)*32 + 8*lh);
        #pragma unroll
        for (int j = 0; j < 4; j++)
            bf[j] = *reinterpret_cast<const f16x8*>(Bs + (64*wn + 16*j + lm)*32 + 8*lh);
        #pragma unroll
        for (int i = 0; i < 4; i++)
            #pragma unroll
            for (int j = 0; j < 4; j++)
                acc[i][j] = __builtin_amdgcn_mfma_f32_16x16x32_f16(af[i], bf[j], acc[i][j], 0, 0, 0);
    }

    // ---- epilogue: LDS transpose + wide stores ----
    __syncthreads();    // all frag reads done; Cs overlays As/Bs
    bool isH = (n0 < 1024);
    int r0 = lh * 4;
    #pragma unroll
    for (int i = 0; i < 4; i++)
        #pragma unroll
        for (int j = 0; j < 4; j++) {
            int row = 64*wm + 16*i + r0;
            int col = 64*wn + 16*j + lm;
            float bias = isH ? bh[n0 + col] : bo[n0 - 1024 + col];
            #pragma unroll
            for (int r = 0; r < 4; r++)
                Cs[(size_t)(row + r)*136 + col] = (f16)(acc[i][j][r] + bias);
        }
    __syncthreads();

    {
        int row = t >> 1;                 // 0..127
        int cp  = (t & 1) * 64;           // column half
        int gm  = m0 + row;               // m = b*512 + t
        const f16* src = Cs + (size_t)row*136 + cp;
        if (isH) {
            int tt = gm & 511, bb = gm >> 9;
            f16* dst = Xh + (size_t)tt*65536 + (size_t)(bb>>4)*16384
                     + (size_t)(bb&15)*1024 + (n0 + cp);
            #pragma unroll
            for (int k = 0; k < 8; ++k)
                *reinterpret_cast<f16x8*>(dst + k*8) =
                    *reinterpret_cast<const f16x8*>(src + k*8);
        } else if (useXo) {
            f16* dst = Xo + (size_t)gm*1024 + (n0 - 1024 + cp);
            #pragma unroll
            for (int k = 0; k < 8; ++k)
                *reinterpret_cast<f16x8*>(dst + k*8) =
                    *reinterpret_cast<const f16x8*>(src + k*8);
        } else {
            float* dst = Out + (size_t)gm*1024 + (n0 - 1024 + cp);
            #pragma unroll
            for (int k = 0; k < 64; ++k)
                dst[k] = (float)src[k];
        }
    }
}

// ---------- fused tree dispatch: vlevel (blockIdx.x < 8) + matrix squaring ----------
// grid (16, nx). r20: vlevel epilogue = two-pass f32 LDS transpose + f16x8 ops.
__global__ __launch_bounds__(256) void k_tree(
    const f16* __restrict__ M, const f16* __restrict__ Src, f16* __restrict__ Dst,
    int srcOff, int srcStep, int dstOff, int dstStep, int aBM,
    const f16* __restrict__ P, f16* __restrict__ Pout)
{
    __shared__ __align__(16) char pool[34816];   // vlevel epilogue Cf[64][136] f32
    int t = threadIdx.x;
    int l = t & 63, w = t >> 6;
    int wm = w >> 1, wn = w & 1;
    int lm = l & 15, lh = l >> 4;

    f32x4 acc[4][4];
    #pragma unroll
    for (int i = 0; i < 4; i++)
        #pragma unroll
        for (int j = 0; j < 4; j++) acc[i][j] = (f32x4){0.f,0.f,0.f,0.f};

    if (blockIdx.x < 8) {
        // ---------------- vlevel body ----------------
        f16* As = (f16*)pool;            // 8 KB
        f16* Bs = (f16*)(pool + 8192);   // 8 KB: [row][32] linear
        float* Cf = (float*)pool;        // epilogue overlay [64][136] f32
        int m0 = blockIdx.y * 128;
        int n0 = blockIdx.x * 128;
        const size_t lgo = (size_t)(l >> 2) * 2048 + (size_t)(l & 3) * 16;
        const int kd0 = m0 >> 6;

        for (int kt = 0; kt < 32; ++kt) {
            __syncthreads();
            if (aBM) {
                size_t slab = (size_t)(srcOff + srcStep * (2*(kd0 + (w>>1))));
                const char* ga = (const char*)Src + slab*131072
                               + (size_t)(w&1)*65536 + (size_t)kt*64 + lgo;
                char* la = (char*)As + w * 2048;
                #pragma unroll
                for (int j = 0; j < 2; ++j)
                    __builtin_amdgcn_global_load_lds(
                        (const __attribute__((address_space(1))) void*)(ga + (size_t)j*32768),
                        (__attribute__((address_space(3))) void*)(la + j*1024), 16, 0, 0);
            } else {
                #pragma unroll
                for (int j = 0; j < 2; ++j) {
                    int ch  = w*2 + j;               // 0..7
                    int kdl = ch >> 2, bgc = ch & 3;
                    size_t slab = (size_t)(srcOff + srcStep * (2*(kd0 + kdl)));
                    const char* gsrc = (const char*)(Src + slab*65536
                                        + (size_t)bgc*16384 + (size_t)kt*512) + (size_t)l*16;
                    __builtin_amdgcn_global_load_lds(
                        (const __attribute__((address_space(1))) void*)gsrc,
                        (__attribute__((address_space(3))) void*)((char*)As + ch*1024), 16, 0, 0);
                }
            }
            {
                const char* gb = (const char*)(M + (size_t)(n0 + w*32) * 1024 + kt*32);
                char* lb = (char*)Bs + w * 2048;
                #pragma unroll
                for (int j = 0; j < 2; ++j)
                    __builtin_amdgcn_global_load_lds(
                        (const __attribute__((address_space(1))) void*)(gb + (size_t)j*32768 + lgo),
                        (__attribute__((address_space(3))) void*)(lb + j*1024), 16, 0, 0);
            }
            asm volatile("s_waitcnt vmcnt(0)" ::: "memory");
            __syncthreads();

            f16x8 af[4], bf[4];
            #pragma unroll
            for (int i = 0; i < 4; i++) {
                if (aBM) af[i] = *reinterpret_cast<const f16x8*>(As + (64*wm + 16*i + lm)*32 + 8*lh);
                else     af[i] = *reinterpret_cast<const f16x8*>(As + wm*2048 + i*512 + lh*128 + lm*8);
            }
            #pragma unroll
            for (int j = 0; j < 4; j++)
                bf[j] = *reinterpret_cast<const f16x8*>(Bs + (64*wn + 16*j + lm)*32 + 8*lh);
            #pragma unroll
            for (int i = 0; i < 4; i++)
                #pragma unroll
                for (int j = 0; j < 4; j++)
                    acc[i][j] = __builtin_amdgcn_mfma_f32_16x16x32_f16(af[i], bf[j], acc[i][j], 0, 0, 0);
        }

        // ---- epilogue: two-pass f32 transpose + wide stores (exact numerics) ----
        int r0 = lh * 4;
        #pragma unroll
        for (int p = 0; p < 2; ++p) {
            __syncthreads();                 // prior reads of pool done
            if (wm == p) {
                #pragma unroll
                for (int i = 0; i < 4; i++)
                    #pragma unroll
                    for (int j = 0; j < 4; j++) {
                        int lrow = 16*i + r0;
                        int col  = 64*wn + 16*j + lm;
                        #pragma unroll
                        for (int r = 0; r < 4; r++)
                            Cf[(size_t)(lrow + r)*136 + col] = acc[i][j][r];
                    }
            }
            __syncthreads();
            {
                int lrow = t >> 2, q = t & 3;     // 64 rows x 4 quarters
                int gm = m0 + p*64 + lrow;
                int kd = gm >> 6, bb = gm & 63;
                size_t aslab = (size_t)(srcOff + srcStep * (2*kd + 1));
                size_t abase = aslab*65536 + (size_t)(bb>>4)*16384;
                size_t dbase = (size_t)(dstOff + dstStep * kd)*65536 + (size_t)(bb>>4)*16384;
                const float* cs = Cf + (size_t)lrow*136 + q*32;
                #pragma unroll
                for (int k = 0; k < 4; ++k) {     // 4 groups of 8 cols
                    int gcol = n0 + q*32 + k*8;   // (gcol & 7) == 0
                    f16x8 av;
                    if (aBM)
                        av = *reinterpret_cast<const f16x8*>(
                            Src + abase + (size_t)(bb&15)*1024 + gcol);
                    else
                        av = *reinterpret_cast<const f16x8*>(
                            Src + abase + (size_t)(gcol>>3)*128 + (size_t)(bb&15)*8);
                    f16x8 hv;
                    #pragma unroll
                    for (int e = 0; e < 8; ++e)
                        hv[e] = (f16)(cs[k*8 + e] + (float)av[e]);
                    *reinterpret_cast<f16x8*>(
                        Dst + dbase + (size_t)(gcol>>3)*128 + (size_t)(bb&15)*8) = hv;
                }
            }
        }
    } else {
        // ---------------- sq body (byte-identical r19) ----------------
        if (blockIdx.y >= 8) return;
        f16 (*As2)[40] = (f16(*)[40])pool;             // 10240 B
        f16 (*Bs2)[40] = (f16(*)[40])(pool + 10240);   // 10240 B
        int m0 = blockIdx.y * 128;
        int n0 = (blockIdx.x - 8) * 128;

        for (int kt = 0; kt < 32; ++kt) {
            __syncthreads();
            #pragma unroll
            for (int c = t; c < 512; c += 256) {       // A rows m, k-contig
                int row = c >> 2, q = c & 3;
                *reinterpret_cast<float4*>(&As2[row][q*8]) =
                    *reinterpret_cast<const float4*>(P + (size_t)(m0+row)*1024 + kt*32 + q*8);
            }
            #pragma unroll
            for (int c = t; c < 512; c += 256) {       // Bs[n][k] = P[k][n0+n]
                int r = c >> 4, q = c & 15;
                f16x8 v = *reinterpret_cast<const f16x8*>(P + (size_t)(kt*32 + r)*1024 + n0 + q*8);
                #pragma unroll
                for (int e = 0; e < 8; ++e) Bs2[q*8+e][r] = v[e];
            }
            __syncthreads();

            f16x8 af[4], bf[4];
            #pragma unroll
            for (int i = 0; i < 4; i++)
                af[i] = *reinterpret_cast<const f16x8*>(&As2[64*wm + 16*i + lm][8*lh]);
            #pragma unroll
            for (int j = 0; j < 4; j++)
                bf[j] = *reinterpret_cast<const f16x8*>(&Bs2[64*wn + 16*j + lm][8*lh]);
            #pragma unroll
            for (int i = 0; i < 4; i++)
                #pragma unroll
                for (int j = 0; j < 4; j++)
                    acc[i][j] = __builtin_amdgcn_mfma_f32_16x16x32_f16(af[i], bf[j], acc[i][j], 0, 0, 0);
        }

        int r0 = lh * 4;
        #pragma unroll
        for (int i = 0; i < 4; i++)
            #pragma unroll
            for (int j = 0; j < 4; j++) {
                int gmb = m0 + 64*wm + 16*i + r0;
                int gn  = n0 + 64*wn + 16*j + lm;
                #pragma unroll
                for (int r = 0; r < 4; r++)
                    Pout[(size_t)(gmb+r)*1024 + gn] = (f16)acc[i][j][r];
            }
    }
}

// ---------- flag-sync recurrence kernel (r13-verified; XV mode-conditional) ----------
__global__ void __launch_bounds__(256) __attribute__((amdgpu_waves_per_eu(1, 1)))
k_chain(
    const f16* __restrict__ W,        // [1024][1024] row-major (A or A16)
    const f16* __restrict__ U,        // u base (slab-packed)
    f16* __restrict__ Hs,
    unsigned int* __restrict__ flags,
    int nstep, int mode, int nch)
{
    int wg = blockIdx.x;
    int r_ = wg & 7, s_ = wg >> 3;
    int g, cg, p, bg;
    if (mode == 1) { g = r_ >> 1; cg = ((r_ & 1) << 3) | s_; p = 0;       bg = g;     }
    else           { g = 2*r_ + (s_ >> 4); cg = s_ & 15;     p = g >> 2;  bg = g & 3; }
    int w  = threadIdx.x >> 6;
    int l  = threadIdx.x & 63;
    int lm = l & 15, lh = l >> 4;
    int ccol = cg * 64 + w * 16 + lm;

    __shared__ f16 hbuf[2][16384];      // 64 KB double-buffered h slab
    __shared__ float lt[4][16][17];

    f16x8 bw[32];
    #pragma unroll
    for (int kt = 0; kt < 32; ++kt)
        bw[kt] = *reinterpret_cast<const f16x8*>(W + (size_t)ccol * 1024 + kt*32 + lh*8);
    #pragma unroll
    for (int kt = 0; kt < 32; ++kt)
        asm volatile("" : "+v"(bw[kt]));

    const int flagBase = g * 16;
    int b_ep = l & 15, cb_ep = l >> 4;
    int cblk = cg*8 + w*2 + cb_ep;

    for (int t = 0; t < nstep; ++t) {
        if (t > 0) {
            if (threadIdx.x < 16) {
                unsigned int tgt = (unsigned int)t;
                const unsigned int* fp = &flags[(flagBase + (int)threadIdx.x) * 8];
                while (__hip_atomic_load(fp, __ATOMIC_RELAXED, __HIP_MEMORY_SCOPE_AGENT) < tgt)
                    __builtin_amdgcn_s_sleep(1);
            }
            __syncthreads();
            asm volatile("" ::: "memory");
        }

        auto slabs = [&](int i, size_t& rS, size_t& wS, size_t& uS) {
            if (mode == 1) { rS = (size_t)(16*t); wS = rS + 16; uS = rS + 8; }
            else { int c = p*nch + i; rS = (size_t)(c*16 + t); wS = rS + 1; uS = rS; }
        };
        auto STAGE = [&](size_t rS, int buf) {
            const char* gsrc = (const char*)Hs + (rS*65536 + (size_t)bg*16384)*2
                             + (size_t)w*8192 + (size_t)l*16;
            char* ldst = (char*)&hbuf[buf][0] + (size_t)w*8192;
            #pragma unroll
            for (int q = 0; q < 8; ++q)
                __builtin_amdgcn_global_load_lds(
                    (const __attribute__((address_space(1))) void*)(gsrc + q*1024),
                    (__attribute__((address_space(3))) void*)(ldst + q*1024),
                    16, 0, 0);
        };
        auto XV = [&](size_t uS) -> f16x8 {
            f16x8 v = {};
            if (l < 32) {
                if (mode == 1)
                    v = *reinterpret_cast<const f16x8*>(
                        U + uS*65536 + (size_t)bg*16384 + (size_t)cblk*128 + b_ep*8);
                else
                    v = *reinterpret_cast<const f16x8*>(
                        U + uS*65536 + (size_t)bg*16384 + (size_t)b_ep*1024 + cblk*8);
            }
            return v;
        };

        // prologue: chunk 0 -> buf 0 (9 memops/wave)
        f16x8 xv0, xv1;
        {
            size_t rS, wS, uS; slabs(0, rS, wS, uS);
            STAGE(rS, 0);
            xv0 = XV(uS);
        }

        for (int i = 0; i < nch; ++i) {
            int nxt = i + 1;
            if (nxt < nch) {
                size_t rS, wS, uS; slabs(nxt, rS, wS, uS);
                STAGE(rS, nxt & 1);
                if (nxt & 1) xv1 = XV(uS); else xv0 = XV(uS);
                asm volatile("s_waitcnt vmcnt(9)" ::: "memory");
            } else {
                asm volatile("s_waitcnt vmcnt(0)" ::: "memory");
            }
            __syncthreads();

            const f16* cbuf = &hbuf[i & 1][0];
            f32x4 a0 = (f32x4){0.f,0.f,0.f,0.f};
            f32x4 a1 = (f32x4){0.f,0.f,0.f,0.f};
            #pragma unroll
            for (int kt = 0; kt < 32; ++kt) {
                f16x8 af = *reinterpret_cast<const f16x8*>(&cbuf[(size_t)(kt*4 + lh)*128 + lm*8]);
                if (kt & 1) a1 = __builtin_amdgcn_mfma_f32_16x16x32_f16(af, bw[kt], a1, 0, 0, 0);
                else        a0 = __builtin_amdgcn_mfma_f32_16x16x32_f16(af, bw[kt], a0, 0, 0, 0);
            }
            f32x4 acc = a0 + a1;

            #pragma unroll
            for (int r = 0; r < 4; ++r)
                lt[w][lh*4 + r][lm] = acc[r];
            // wave-private RAW through LDS (compiler inserts lgkmcnt)

            if (l < 32) {
                f16x8 xvc = (i & 1) ? xv1 : xv0;
                size_t rS, wS, uS; slabs(i, rS, wS, uS);
                f16x8 hv;
                #pragma unroll
                for (int e = 0; e < 8; ++e)
                    hv[e] = (f16)(lt[w][b_ep][cb_ep*8 + e] + (float)xvc[e]);
                f16* dst = Hs + wS*65536 + (size_t)bg*16384 + (size_t)cblk*128 + b_ep*8;
                i32x4 iv = __builtin_bit_cast(i32x4, hv);
                asm volatile("global_store_dwordx4 %0, %1, off sc0 sc1"
                             :: "v"(dst), "v"(iv) : "memory");
            }
            __syncthreads();   // all waves done reading buf[i&1] before it is restaged
        }

        asm volatile("s_waitcnt vmcnt(0)" ::: "memory");
        __syncthreads();
        if (threadIdx.x == 0) {
            unsigned int* fp = &flags[(flagBase + cg)*8];
            unsigned int val = (unsigned int)(t + 1);
            asm volatile("global_store_dword %0, %1, off sc0 sc1"
                         :: "v"(fp), "v"(val) : "memory");
        }
    }
}

// ---------- phase 3: output GEMM (r20 epilogue: two-pass f32 transpose) ----------
// useXo: Out = Xo + Hs@Wro^T (pure write). fallback: Out += Hs@Wro^T.
__global__ __launch_bounds__(256) void k_gemm2(
    const f16* __restrict__ Hs, const f16* __restrict__ Bm, float* __restrict__ Out,
    const f16* __restrict__ Xo, int useXo)
{
    __shared__ __align__(16) char pool[34816];   // K-loop 16 KB; epilogue Cf[64][136] f32
    f16* As = (f16*)pool;            // 8 KB: [ttloc2][bg4][kblk4][b16][e8]
    f16* Bs = (f16*)(pool + 8192);   // 8 KB
    float* Cf = (float*)pool;        // epilogue overlay
    int m0 = blockIdx.y * 128;          // m' = t*64 + b
    int n0 = blockIdx.x * 128;
    int t = threadIdx.x;
    int l = t & 63, w = t >> 6;
    int wm = w >> 1, wn = w & 1;
    int lm = l & 15, lh = l >> 4;

    f32x4 acc[4][4];
    #pragma unroll
    for (int i = 0; i < 4; i++)
        #pragma unroll
        for (int j = 0; j < 4; j++) acc[i][j] = (f32x4){0.f,0.f,0.f,0.f};

    const size_t lgo = (size_t)(l >> 2) * 2048 + (size_t)(l & 3) * 16;
    const int tt0 = m0 >> 6;

    for (int kt = 0; kt < 32; ++kt) {
        __syncthreads();
        {
            #pragma unroll
            for (int j = 0; j < 2; ++j) {
                int ch  = w*2 + j;               // 0..7
                int ttl = ch >> 2, bgc = ch & 3;
                const char* gsrc = (const char*)(Hs + (size_t)(tt0 + ttl)*65536
                                    + (size_t)bgc*16384 + (size_t)kt*512) + (size_t)l*16;
                __builtin_amdgcn_global_load_lds(
                    (const __attribute__((address_space(1))) void*)gsrc,
                    (__attribute__((address_space(3))) void*)((char*)As + ch*1024), 16, 0, 0);
            }
            const char* gb = (const char*)(Bm + (size_t)(n0 + w*32) * 1024 + kt*32);
            char* lb = (char*)Bs + w * 2048;
            #pragma unroll
            for (int j = 0; j < 2; ++j)
                __builtin_amdgcn_global_load_lds(
                    (const __attribute__((address_space(1))) void*)(gb + (size_t)j*32768 + lgo),
                    (__attribute__((address_space(3))) void*)(lb + j*1024), 16, 0, 0);
        }
        asm volatile("s_waitcnt vmcnt(0)" ::: "memory");
        __syncthreads();

        f16x8 af[4], bf[4];
        #pragma unroll
        for (int i = 0; i < 4; i++)
            af[i] = *reinterpret_cast<const f16x8*>(As + wm*2048 + i*512 + lh*128 + lm*8);
        #pragma unroll
        for (int j = 0; j < 4; j++)
            bf[j] = *reinterpret_cast<const f16x8*>(Bs + (64*wn + 16*j + lm)*32 + 8*lh);
        #pragma unroll
        for (int i = 0; i < 4; i++)
            #pragma unroll
            for (int j = 0; j < 4; j++)
                acc[i][j] = __builtin_amdgcn_mfma_f32_16x16x32_f16(af[i], bf[j], acc[i][j], 0, 0, 0);
    }

    // ---- epilogue: two-pass f32 transpose + wide stores (exact numerics) ----
    int r0 = lh * 4;
    #pragma unroll
    for (int p = 0; p < 2; ++p) {
        __syncthreads();                 // prior reads of pool done
        if (wm == p) {
            #pragma unroll
            for (int i = 0; i < 4; i++)
                #pragma unroll
                for (int j = 0; j < 4; j++) {
                    int lrow = 16*i + r0;
                    int col  = 64*wn + 16*j + lm;
                    #pragma unroll
                    for (int r = 0; r < 4; r++)
                        Cf[(size_t)(lrow + r)*136 + col] = acc[i][j][r];
                }
        }
        __syncthreads();
        {
            int lrow = t >> 2, q = t & 3;     // 64 rows x 4 quarters
            int gm = m0 + p*64 + lrow;        // m' = t*64 + b
            int bb = gm & 63, tt = gm >> 6;
            size_t o = ((size_t)bb*512 + tt)*1024 + n0 + q*32;
            const float* cs = Cf + (size_t)lrow*136 + q*32;
            if (useXo) {
                #pragma unroll
                for (int k = 0; k < 4; ++k) {
                    f16x8 xv = *reinterpret_cast<const f16x8*>(Xo + o + k*8);
                    f32x4 v0, v1;
                    #pragma unroll
                    for (int e = 0; e < 4; ++e) v0[e] = cs[k*8 + e] + (float)xv[e];
                    #pragma unroll
                    for (int e = 0; e < 4; ++e) v1[e] = cs[k*8 + 4 + e] + (float)xv[4 + e];
                    *reinterpret_cast<f32x4*>(Out + o + k*8)     = v0;
                    *reinterpret_cast<f32x4*>(Out + o + k*8 + 4) = v1;
                }
            } else {
                #pragma unroll
                for (int k = 0; k < 32; ++k)
                    Out[o + k] += cs[k];
            }
        }
    }
}

// ---------- workspace layout (bytes) ----------
// [0, 4M)      Wx (gemm1); afterwards Pa @0, Pb @2M (A-power ping-pong)
// [4M, 8M)     Wr  (rows 0..1023 = A = Wrh, rows 1024..2047 = Wro)
// [8M, 72M)    Xh  [512 b-major slabs]
// [72M, 136M)  Hs  [512 Hs-layout slabs]; ALSO Xf pre-gemm1 (dead after);
//              then V1 -> slabs 1..256, V2 -> odd 257.., V3 -> 2+4m, V4 -> 8+16m
// [136M, +16K) flags u32[4096]: chain bank [0,512), fill bank [512,2560)
// [144M, 208M) Xo f16 [32768][1024]  (only if ws_size >= 208M)

extern "C" void kernel_launch(void* const* d_in, const int* in_sizes, int n_in,
                              void* d_out, int out_size, void* d_ws, size_t ws_size,
                              hipStream_t stream) {
    const float* X  = (const float*)d_in[0];
    const float* H0 = (const float*)d_in[1];
    const float* Wh = (const float*)d_in[2];
    const float* bh = (const float*)d_in[3];
    const float* Wo = (const float*)d_in[4];
    const float* bo = (const float*)d_in[5];
    float* Out = (float*)d_out;

    char* ws = (char*)d_ws;
    f16* Wx = (f16*)(ws);
    f16* Pa = (f16*)(ws);                               // aliases Wx (dead after gemm1)
    f16* Pb = (f16*)(ws + (size_t)2*1024*1024);
    f16* Wr = (f16*)(ws + (size_t)4*1024*1024);
    f16* Xh = (f16*)(ws + (size_t)8*1024*1024);
    f16* Hs = (f16*)(ws + (size_t)8*1024*1024 + (size_t)M_TOT*1024*2);
    f16* Xf = Hs;                                       // aliases Hs (dead until after gemm1)
    unsigned int* flags = (unsigned int*)(ws + (size_t)8*1024*1024 + (size_t)2*M_TOT*1024*2);

    const size_t XO_OFF = (size_t)144*1024*1024;
    int useXo = (ws_size >= XO_OFF + (size_t)M_TOT*1024*2) ? 1 : 0;
    f16* Xo = (f16*)(ws + XO_OFF);

    hipLaunchKernelGGL(k_prep, dim3(16384 + 2048), dim3(256), 0, stream, Wh, Wo, X, Wx, Wr, Xf);
    hipLaunchKernelGGL(k_gemm1, dim3(16, 256), dim3(256), 0, stream, Xf, Wx, bh, bo, Xh, Out, Xo, useXo);
    hipLaunchKernelGGL(k_init, dim3(48), dim3(256), 0, stream, H0, Hs, flags);  // after gemm1: Xf dead

    // fused tree: each dispatch = vlevel (8 x nx blocks) + squaring (8 x 8)
    hipLaunchKernelGGL(k_tree, dim3(16, 128), dim3(256), 0, stream, Wr, Xh, Hs, 0,1, 1,1,   1, Wr, Pa); // V1 + A2
    hipLaunchKernelGGL(k_tree, dim3(16, 64),  dim3(256), 0, stream, Pa, Hs, Hs, 1,1, 257,2,  0, Pa, Pb); // V2 + A4
    hipLaunchKernelGGL(k_tree, dim3(16, 32),  dim3(256), 0, stream, Pb, Hs, Hs, 257,2, 2,4,  0, Pb, Pa); // V3 + A8
    hipLaunchKernelGGL(k_tree, dim3(16, 16),  dim3(256), 0, stream, Pa, Hs, Hs, 2,4, 8,16,   0, Pa, Pb); // V4 + A16

    // chain: h_{16(t+1)} = A16 h_{16t} + v4_t   (31 steps, 64 WGs, flag bank 0)
    {
        int nstep = 31, mode = 1, nch = 1;
        void* args[] = { (void*)&Pb, (void*)&Hs, (void*)&Hs, (void*)&flags,
                         (void*)&nstep, (void*)&mode, (void*)&nch };
        if (hipLaunchCooperativeKernel((const void*)k_chain, dim3(64), dim3(256),
                                       args, 0, stream) != hipSuccess) {
            hipLaunchKernelGGL(k_chain, dim3(64), dim3(256), 0, stream,
                               Pb, Hs, Hs, flags, 31, 1, 1);
        }
    }

    // fill: h_{c*16+t+1} = A h_{c*16+t} + u(Xh b-major)  (15 steps, 256 WGs, bank 512)
    {
        unsigned int* flags2 = flags + 512;
        int nstep = 15, mode = 2, nch = 8;
        void* args[] = { (void*)&Wr, (void*)&Xh, (void*)&Hs, (void*)&flags2,
                         (void*)&nstep, (void*)&mode, (void*)&nch };
        if (hipLaunchCooperativeKernel((const void*)k_chain, dim3(256), dim3(256),
                                       args, 0, stream) != hipSuccess) {
            hipLaunchKernelGGL(k_chain, dim3(256), dim3(256), 0, stream,
                               Wr, Xh, Hs, flags2, 15, 2, 8);
        }
    }

    f16* Wro = Wr + (size_t)1024*1024;
    hipLaunchKernelGGL(k_gemm2, dim3(8, 256), dim3(256), 0, stream, Hs, Wro, Out, Xo, useXo);
}